// Round 1
// baseline (198.974 us; speedup 1.0000x reference)
//
#include <hip/hip_runtime.h>
#include <math.h>

#define NQ 6
#define DIM 64
#define DM_N 4096      // 64*64 density-matrix entries
#define BLK 256
#define HID 256
#define INDIM 784
#define P1Q 0.001f
#define P2Q 0.01f

#define OP_GATE 0
#define OP_CNOT 1
#define OP_DEP1 2
#define OP_DEP2 3

__device__ __forceinline__ float2 cmul(float2 a, float2 b) {
    return make_float2(a.x * b.x - a.y * b.y, a.x * b.y + a.y * b.x);
}
__device__ __forceinline__ float2 cmulc(float2 a, float2 b) { // a * conj(b)
    return make_float2(a.x * b.x + a.y * b.y, a.y * b.x - a.x * b.y);
}
__device__ __forceinline__ float2 cadd(float2 a, float2 b) {
    return make_float2(a.x + b.x, a.y + b.y);
}

// Index layout: idx = ket*64 + bra. Wire w: ket bit (11-w), bra bit (5-w)
// (wire 0 = MSB, matching the reference's axis ordering).

__global__ __launch_bounds__(BLK, 1)
void nqm_kernel(const float* __restrict__ x, const float* __restrict__ W1,
                const float* __restrict__ b1, const float* __restrict__ ln_g,
                const float* __restrict__ ln_b, const float* __restrict__ W2,
                const float* __restrict__ b2, const float* __restrict__ shared_w,
                const float* __restrict__ task_w, const float* __restrict__ Wp,
                const float* __restrict__ bp, float* __restrict__ out)
{
    __shared__ float2 dm[DM_N];          // 32 KB density matrix
    __shared__ float4 xrow[INDIM / 4];   // staged input row
    __shared__ float red[4], red2[4];    // layernorm wave partials
    __shared__ float zpart[4][8];        // z wave partials
    __shared__ float2 Umat[36][4];       // 0..5: RY(z_i); 6..35: Rot gates
    __shared__ float bcast[2];           // mu, rstd
    __shared__ unsigned int ops[96];     // circuit op list

    const int tid = threadIdx.x;
    const int b = blockIdx.x;
    const int wid = tid >> 6;
    const int lane = tid & 63;

    // ---------------- encoder: h = relu(x @ W1^T + b1) ----------------
    const float4* xg = (const float4*)(x + (size_t)b * INDIM);
    if (tid < INDIM / 4) xrow[tid] = xg[tid];
    __syncthreads();

    const float4* w1v = (const float4*)(W1 + (size_t)tid * INDIM);
    float acc = b1[tid];
    #pragma unroll 8
    for (int k = 0; k < INDIM / 4; ++k) {
        float4 wv = w1v[k];
        float4 xv = xrow[k];
        acc = fmaf(wv.x, xv.x, acc);
        acc = fmaf(wv.y, xv.y, acc);
        acc = fmaf(wv.z, xv.z, acc);
        acc = fmaf(wv.w, xv.w, acc);
    }
    float h = fmaxf(acc, 0.0f);

    // layernorm reduction
    float s = h, s2 = h * h;
    #pragma unroll
    for (int off = 32; off > 0; off >>= 1) {
        s  += __shfl_down(s, off, 64);
        s2 += __shfl_down(s2, off, 64);
    }
    if (lane == 0) { red[wid] = s; red2[wid] = s2; }
    __syncthreads();
    if (tid == 0) {
        float ts  = red[0] + red[1] + red[2] + red[3];
        float ts2 = red2[0] + red2[1] + red2[2] + red2[3];
        float mu  = ts * (1.0f / HID);
        float var = ts2 * (1.0f / HID) - mu * mu;
        bcast[0] = mu;
        bcast[1] = rsqrtf(var + 1e-5f);
    }
    __syncthreads();
    float hnj = (h - bcast[0]) * bcast[1] * ln_g[tid] + ln_b[tid];

    // z partials: z_i = tanh(sum_j hn_j * W2[i][j] + b2[i])
    float p[NQ];
    #pragma unroll
    for (int i = 0; i < NQ; ++i) p[i] = hnj * W2[i * HID + tid];
    #pragma unroll
    for (int off = 32; off > 0; off >>= 1) {
        #pragma unroll
        for (int i = 0; i < NQ; ++i) p[i] += __shfl_down(p[i], off, 64);
    }
    if (lane == 0) {
        #pragma unroll
        for (int i = 0; i < NQ; ++i) zpart[wid][i] = p[i];
    }
    __syncthreads();

    // ---------------- gate matrices + op list + dm init ----------------
    if (tid < NQ) {
        // RY(z_i * pi): [[c,-s],[s,c]], c=cos(theta/2)
        float z = zpart[0][tid] + zpart[1][tid] + zpart[2][tid] + zpart[3][tid] + b2[tid];
        z = tanhf(z);
        float sn, c;
        sincosf(z * 1.57079632679489662f, &sn, &c);
        Umat[tid][0] = make_float2(c, 0.f);
        Umat[tid][1] = make_float2(-sn, 0.f);
        Umat[tid][2] = make_float2(sn, 0.f);
        Umat[tid][3] = make_float2(c, 0.f);
    } else if (tid < 36) {
        // Rot(phi,theta,omega) = RZ(omega) RY(theta) RZ(phi)
        int g = tid - NQ;
        int layer = g / NQ;
        int wire = g % NQ;
        const float* w = (layer < 3) ? (shared_w + (layer * NQ + wire) * 3)
                                     : (task_w + ((layer - 3) * NQ + wire) * 3);
        float phi = w[0], theta = w[1], omega = w[2];
        float sn, c;
        sincosf(theta * 0.5f, &sn, &c);
        float sp, cp, sm, cm;
        sincosf(-0.5f * (phi + omega), &sp, &cp);  // ep = cp + i*sp
        sincosf( 0.5f * (phi - omega), &sm, &cm);  // em = cm + i*sm
        Umat[tid][0] = make_float2(cp * c,   sp * c);   // ep*c
        Umat[tid][1] = make_float2(-cm * sn, -sm * sn); // -em*s
        Umat[tid][2] = make_float2(cm * sn,  -sm * sn); // conj(em)*s
        Umat[tid][3] = make_float2(cp * c,   -sp * c);  // conj(ep)*c
    }
    if (tid == BLK - 1) {
        int n = 0, g = NQ;
        for (int i = 0; i < NQ; ++i) {                  // RY + depol per qubit
            ops[n++] = OP_GATE | (i << 4) | (i << 16);
            ops[n++] = OP_DEP1 | (i << 4);
        }
        for (int l = 0; l < 3; ++l) {                   // shared entangling
            for (int i = 0; i < NQ; ++i) ops[n++] = OP_GATE | (i << 4) | ((g++) << 16);
            int r = (l % (NQ - 1)) + 1;
            for (int i = 0; i < NQ; ++i)
                ops[n++] = OP_CNOT | (i << 4) | (((i + r) % NQ) << 10);
        }
        for (int i = 0; i < NQ; ++i)     ops[n++] = OP_DEP1 | (i << 4);
        for (int i = 0; i < NQ - 1; ++i) ops[n++] = OP_DEP2 | (i << 4);
        for (int l = 0; l < 2; ++l) {                   // task entangling
            for (int i = 0; i < NQ; ++i) ops[n++] = OP_GATE | (i << 4) | ((g++) << 16);
            int r = (l % (NQ - 1)) + 1;
            for (int i = 0; i < NQ; ++i)
                ops[n++] = OP_CNOT | (i << 4) | (((i + r) % NQ) << 10);
        }
        for (int i = 0; i < NQ; ++i) ops[n++] = OP_DEP1 | (i << 4);
        // n == 89
    }
    #pragma unroll
    for (int k = 0; k < DM_N / BLK; ++k) {
        int i = tid + k * BLK;
        dm[i] = make_float2(i == 0 ? 1.0f : 0.0f, 0.0f);
    }
    __syncthreads();

    // ---------------- circuit ----------------
    for (int op = 0; op < 89; ++op) {
        unsigned int o = ops[op];
        int type = o & 15;
        int a0 = (o >> 4) & 63;
        int a1 = (o >> 10) & 63;
        int gi = (o >> 16) & 255;
        if (type == OP_GATE) {
            // rho -> U rho U^dag on wire a0, fused ket+bra over 2x2 blocks
            const int mk = 1 << (11 - a0);
            const int mb = 1 << (5 - a0);
            float2 u0 = Umat[gi][0], u1 = Umat[gi][1];
            float2 u2 = Umat[gi][2], u3 = Umat[gi][3];
            #pragma unroll
            for (int k = 0; k < 4; ++k) {
                int pq = tid + k * BLK;             // 1024 quadruples
                int lowb = pq & (mb - 1);
                int t1 = ((pq ^ lowb) << 1) | lowb; // insert 0 at bra bit
                int lowk = t1 & (mk - 1);
                int idx = ((t1 ^ lowk) << 1) | lowk;// insert 0 at ket bit
                float2 m00 = dm[idx];
                float2 m01 = dm[idx | mb];
                float2 m10 = dm[idx | mk];
                float2 m11 = dm[idx | mk | mb];
                float2 t00 = cadd(cmul(u0, m00), cmul(u1, m10));
                float2 t01 = cadd(cmul(u0, m01), cmul(u1, m11));
                float2 t10 = cadd(cmul(u2, m00), cmul(u3, m10));
                float2 t11 = cadd(cmul(u2, m01), cmul(u3, m11));
                dm[idx]           = cadd(cmulc(t00, u0), cmulc(t01, u1));
                dm[idx | mb]      = cadd(cmulc(t00, u2), cmulc(t01, u3));
                dm[idx | mk]      = cadd(cmulc(t10, u0), cmulc(t11, u1));
                dm[idx | mk | mb] = cadd(cmulc(t10, u2), cmulc(t11, u3));
            }
        } else if (type == OP_CNOT) {
            // pure index involution: flip target bit where control bit set (ket & bra)
            const int mkc = 1 << (11 - a0), mbc = 1 << (5 - a0);
            const int mkt = 1 << (11 - a1), mbt = 1 << (5 - a1);
            #pragma unroll 4
            for (int k = 0; k < DM_N / BLK; ++k) {
                int idx = tid + k * BLK;
                int j = idx;
                if (idx & mkc) j ^= mkt;
                if (idx & mbc) j ^= mbt;
                if (j > idx) {              // owner of smaller index swaps; orbits disjoint
                    float2 va = dm[idx];
                    float2 vb = dm[j];
                    dm[idx] = vb;
                    dm[j] = va;
                }
            }
        } else {
            // depolarize wire a0: diag blocks mix (2p/3), off-diag scale (1-4p/3)
            const float pp = (type == OP_DEP1) ? P1Q : P2Q;
            const float wd = 1.0f - 2.0f * pp * (1.0f / 3.0f);
            const float wx = 2.0f * pp * (1.0f / 3.0f);
            const float wo = 1.0f - 4.0f * pp * (1.0f / 3.0f);
            const int mk = 1 << (11 - a0);
            const int mb = 1 << (5 - a0);
            #pragma unroll
            for (int k = 0; k < 4; ++k) {
                int pq = tid + k * BLK;
                int lowb = pq & (mb - 1);
                int t1 = ((pq ^ lowb) << 1) | lowb;
                int lowk = t1 & (mk - 1);
                int idx = ((t1 ^ lowk) << 1) | lowk;
                float2 v00 = dm[idx];
                float2 v01 = dm[idx | mb];
                float2 v10 = dm[idx | mk];
                float2 v11 = dm[idx | mk | mb];
                dm[idx]           = make_float2(wd * v00.x + wx * v11.x, wd * v00.y + wx * v11.y);
                dm[idx | mb]      = make_float2(wo * v01.x, wo * v01.y);
                dm[idx | mk]      = make_float2(wo * v10.x, wo * v10.y);
                dm[idx | mk | mb] = make_float2(wd * v11.x + wx * v00.x, wd * v11.y + wx * v00.y);
            }
        }
        __syncthreads();
    }

    // ---------------- measurement + linear head ----------------
    if (wid == 0) {
        float pr = dm[lane * (DIM + 1)].x;   // diagonal probability, lane = basis state
        float ev[NQ];
        #pragma unroll
        for (int i = 0; i < NQ; ++i)
            ev[i] = ((lane >> (5 - i)) & 1) ? -pr : pr;
        #pragma unroll
        for (int off = 32; off > 0; off >>= 1) {
            #pragma unroll
            for (int i = 0; i < NQ; ++i) ev[i] += __shfl_down(ev[i], off, 64);
        }
        if (lane == 0) {
            #pragma unroll
            for (int j = 0; j < 2; ++j) {
                float o = bp[j];
                #pragma unroll
                for (int i = 0; i < NQ; ++i) o = fmaf(ev[i], Wp[j * NQ + i], o);
                out[b * 2 + j] = o;
            }
        }
    }
}

extern "C" void kernel_launch(void* const* d_in, const int* in_sizes, int n_in,
                              void* d_out, int out_size, void* d_ws, size_t ws_size,
                              hipStream_t stream) {
    (void)in_sizes; (void)n_in; (void)d_ws; (void)ws_size; (void)out_size;
    const float* x        = (const float*)d_in[0];
    const float* W1       = (const float*)d_in[1];
    const float* b1       = (const float*)d_in[2];
    const float* ln_g     = (const float*)d_in[3];
    const float* ln_b     = (const float*)d_in[4];
    const float* W2       = (const float*)d_in[5];
    const float* b2       = (const float*)d_in[6];
    const float* shared_w = (const float*)d_in[7];
    const float* task_w   = (const float*)d_in[8];
    const float* Wp       = (const float*)d_in[9];
    const float* bp       = (const float*)d_in[10];
    float* out = (float*)d_out;

    hipLaunchKernelGGL(nqm_kernel, dim3(256), dim3(BLK), 0, stream,
                       x, W1, b1, ln_g, ln_b, W2, b2, shared_w, task_w, Wp, bp, out);
}

// Round 2
// 119.621 us; speedup vs baseline: 1.6634x; 1.6634x over previous
//
#include <hip/hip_runtime.h>
#include <math.h>

#define NQ 6
#define DIM 64
#define DM_N 4096      // 64*64 density-matrix entries
#define BLK 1024
#define HID 256
#define INDIM 784

// depolarizing channel constants (diag mix wd/wx, off-diag scale wo)
#define PW1 0.001f
#define PW2 0.01f
constexpr float WD1 = 1.f - 2.f * PW1 / 3.f;
constexpr float WX1 = 2.f * PW1 / 3.f;
constexpr float WO1 = 1.f - 4.f * PW1 / 3.f;
constexpr float WD2 = 1.f - 2.f * PW2 / 3.f;
constexpr float WX2 = 2.f * PW2 / 3.f;
constexpr float WO2 = 1.f - 4.f * PW2 / 3.f;
// composition dep1 then dep2 on same wire
constexpr float WDc = WD1 * WD2 + WX1 * WX2;
constexpr float WXc = WD1 * WX2 + WX1 * WD2;
constexpr float WOc = WO1 * WO2;

__device__ __forceinline__ float2 cmul(float2 a, float2 b) {
    return make_float2(a.x * b.x - a.y * b.y, a.x * b.y + a.y * b.x);
}
__device__ __forceinline__ float2 cmulc(float2 a, float2 b) { // a * conj(b)
    return make_float2(a.x * b.x + a.y * b.y, a.y * b.x - a.x * b.y);
}
__device__ __forceinline__ float2 cadd(float2 a, float2 b) {
    return make_float2(a.x + b.x, a.y + b.y);
}

// Index layout: idx = ket*64 + bra. Wire w: ket bit (11-w), bra bit (5-w), wire 0 = MSB.

__global__ __launch_bounds__(BLK)
void nqm_kernel(const float* __restrict__ x, const float* __restrict__ W1,
                const float* __restrict__ b1, const float* __restrict__ ln_g,
                const float* __restrict__ ln_b, const float* __restrict__ W2,
                const float* __restrict__ b2, const float* __restrict__ shared_w,
                const float* __restrict__ task_w, const float* __restrict__ Wp,
                const float* __restrict__ bp, float* __restrict__ out)
{
    __shared__ __align__(16) float2 dm[DM_N];   // 32 KB density matrix
    __shared__ float4 xrow[INDIM / 4];          // staged input row
    __shared__ float hpart[1024];               // 4-way split GEMM partials
    __shared__ float2 Umat[36][4];              // 6..35: Rot gates (0..5 unused)
    __shared__ float rho1q[NQ][4];              // initial per-qubit real 2x2 dms
    __shared__ int permtab[3][64];              // CNOT-ring inverse perms, r=1,2,3
    __shared__ float red[4], red2[4];           // layernorm wave partials
    __shared__ float zpart[4][8];               // z wave partials
    __shared__ float bcast[2];                  // mu, rstd

    const int tid = threadIdx.x;
    const int b = blockIdx.x;
    const int lane = tid & 63;

    // ---------------- encoder: h = relu(x @ W1^T + b1) ----------------
    if (tid < INDIM / 4) xrow[tid] = ((const float4*)(x + (size_t)b * INDIM))[tid];
    __syncthreads();

    {   // 4 threads per hidden unit, 49 float4 each
        const int u = tid & 255, p = tid >> 8;
        const float4* w1v = (const float4*)(W1 + (size_t)u * INDIM) + p * 49;
        const float4* xv4 = xrow + p * 49;
        float acc = 0.0f;
        #pragma unroll 7
        for (int k = 0; k < 49; ++k) {
            float4 wv = w1v[k];
            float4 xv = xv4[k];
            acc = fmaf(wv.x, xv.x, acc);
            acc = fmaf(wv.y, xv.y, acc);
            acc = fmaf(wv.z, xv.z, acc);
            acc = fmaf(wv.w, xv.w, acc);
        }
        hpart[p * 256 + u] = acc;
    }
    __syncthreads();

    float h = 0.0f;
    if (tid < 256) {
        h = hpart[tid] + hpart[256 + tid] + hpart[512 + tid] + hpart[768 + tid] + b1[tid];
        h = fmaxf(h, 0.0f);
        float s = h, s2 = h * h;
        #pragma unroll
        for (int off = 32; off > 0; off >>= 1) {
            s  += __shfl_down(s, off, 64);
            s2 += __shfl_down(s2, off, 64);
        }
        if (lane == 0) { red[tid >> 6] = s; red2[tid >> 6] = s2; }
    }
    __syncthreads();
    if (tid == 0) {
        float ts  = red[0] + red[1] + red[2] + red[3];
        float ts2 = red2[0] + red2[1] + red2[2] + red2[3];
        float mu  = ts * (1.0f / HID);
        float var = ts2 * (1.0f / HID) - mu * mu;
        bcast[0] = mu;
        bcast[1] = rsqrtf(var + 1e-5f);
    }
    __syncthreads();
    if (tid < 256) {
        float hnj = (h - bcast[0]) * bcast[1] * ln_g[tid] + ln_b[tid];
        float p[NQ];
        #pragma unroll
        for (int i = 0; i < NQ; ++i) p[i] = hnj * W2[i * HID + tid];
        #pragma unroll
        for (int off = 32; off > 0; off >>= 1) {
            #pragma unroll
            for (int i = 0; i < NQ; ++i) p[i] += __shfl_down(p[i], off, 64);
        }
        if (lane == 0) {
            #pragma unroll
            for (int i = 0; i < NQ; ++i) zpart[tid >> 6][i] = p[i];
        }
    }
    __syncthreads();

    // ------------- gate matrices, init dms, CNOT-ring perm tables -------------
    if (tid < NQ) {
        // per-qubit initial dm: dep(RY(z*pi)|0><0|RY^T), real 2x2
        float z = zpart[0][tid] + zpart[1][tid] + zpart[2][tid] + zpart[3][tid] + b2[tid];
        z = tanhf(z);
        float sn, c;
        sincosf(z * 1.57079632679489662f, &sn, &c);
        float c2 = c * c, s2 = sn * sn, cs = c * sn;
        rho1q[tid][0] = WD1 * c2 + WX1 * s2;  // [k=0][b=0]
        rho1q[tid][1] = WO1 * cs;             // [0][1]
        rho1q[tid][2] = WO1 * cs;             // [1][0]
        rho1q[tid][3] = WD1 * s2 + WX1 * c2;  // [1][1]
    } else if (tid < 36) {
        // Rot(phi,theta,omega) = RZ(omega) RY(theta) RZ(phi)
        int g = tid - NQ;
        int layer = g / NQ;
        int wire = g % NQ;
        const float* w = (layer < 3) ? (shared_w + (layer * NQ + wire) * 3)
                                     : (task_w + ((layer - 3) * NQ + wire) * 3);
        float phi = w[0], theta = w[1], omega = w[2];
        float sn, c;
        sincosf(theta * 0.5f, &sn, &c);
        float sp, cp, sm, cm;
        sincosf(-0.5f * (phi + omega), &sp, &cp);  // ep = cp + i*sp
        sincosf( 0.5f * (phi - omega), &sm, &cm);  // em = cm + i*sm
        Umat[tid][0] = make_float2(cp * c,   sp * c);   // ep*c
        Umat[tid][1] = make_float2(-cm * sn, -sm * sn); // -em*s
        Umat[tid][2] = make_float2(cm * sn,  -sm * sn); // conj(em)*s
        Umat[tid][3] = make_float2(cp * c,   -sp * c);  // conj(ep)*c
    } else if (tid < 36 + 3 * 64) {
        // permtab[ri][s] = pi^{-1}(s) for CNOT ring with range r = ri+1:
        // forward ring applies CNOT(control=i, target=(i+r)%6) for i=0..5;
        // inverse applies them in reverse order (each CNOT self-inverse).
        int t = tid - 36;
        int ri = t >> 6, s = t & 63, r = ri + 1;
        int v = s;
        #pragma unroll
        for (int i = 5; i >= 0; --i) {
            int tw = (i + r) % 6;
            if ((v >> (5 - i)) & 1) v ^= 1 << (5 - tw);
        }
        permtab[ri][s] = v;
    }
    __syncthreads();

    // ---------------- init pass: dm = tensor product of rho1q ----------------
    #pragma unroll
    for (int k = 0; k < 4; ++k) {
        int idx = tid + k * BLK;
        int K = idx >> 6, B = idx & 63;
        float v = 1.0f;
        #pragma unroll
        for (int q = 0; q < NQ; ++q) {
            int kb = (K >> (5 - q)) & 1;
            int bb = (B >> (5 - q)) & 1;
            v *= rho1q[q][kb * 2 + bb];
        }
        dm[idx] = make_float2(v, 0.0f);
    }
    __syncthreads();

    // ---------------- 5 entangling layers ----------------
    const int rtab[5] = {0, 1, 2, 0, 1};  // perm table index per layer (r-1)
    for (int l = 0; l < 5; ++l) {
        // 6 rot passes (task layer 1 additionally absorbs the mid-circuit deps)
        #pragma unroll
        for (int i = 0; i < NQ; ++i) {
            const int gi = 6 + l * 6 + i;
            float2 u0 = Umat[gi][0], u1 = Umat[gi][1];
            float2 u2 = Umat[gi][2], u3 = Umat[gi][3];
            const int mb = 1 << (5 - i);
            const int mk = mb << 6;
            int pq = tid;
            int lowb = pq & (mb - 1);
            int t1 = ((pq ^ lowb) << 1) | lowb;     // insert 0 at bra bit
            int lowk = t1 & (mk - 1);
            int idx = ((t1 ^ lowk) << 1) | lowk;    // insert 0 at ket bit
            float2 m00, m01, m10, m11;
            if (i == 5) {                            // mb==1: adjacent pairs, b128
                float4 lo = *reinterpret_cast<const float4*>(&dm[idx]);
                float4 hi = *reinterpret_cast<const float4*>(&dm[idx + 64]);
                m00 = make_float2(lo.x, lo.y); m01 = make_float2(lo.z, lo.w);
                m10 = make_float2(hi.x, hi.y); m11 = make_float2(hi.z, hi.w);
            } else {
                m00 = dm[idx];      m01 = dm[idx | mb];
                m10 = dm[idx | mk]; m11 = dm[idx | mk | mb];
            }
            float2 t00 = cadd(cmul(u0, m00), cmul(u1, m10));
            float2 t01 = cadd(cmul(u0, m01), cmul(u1, m11));
            float2 t10 = cadd(cmul(u2, m00), cmul(u3, m10));
            float2 t11 = cadd(cmul(u2, m01), cmul(u3, m11));
            float2 r00 = cadd(cmulc(t00, u0), cmulc(t01, u1));
            float2 r01 = cadd(cmulc(t00, u2), cmulc(t01, u3));
            float2 r10 = cadd(cmulc(t10, u0), cmulc(t11, u1));
            float2 r11 = cadd(cmulc(t10, u2), cmulc(t11, u3));
            if (l == 3) {
                // fold mid-circuit deps (dep commutes with same-wire unitary):
                // wires 0..4 get dep1*dep2 combo, wire 5 dep1 only
                float wd = (i < 5) ? WDc : WD1;
                float wx = (i < 5) ? WXc : WX1;
                float wo = (i < 5) ? WOc : WO1;
                float2 f00 = make_float2(wd * r00.x + wx * r11.x, wd * r00.y + wx * r11.y);
                float2 f11 = make_float2(wd * r11.x + wx * r00.x, wd * r11.y + wx * r00.y);
                r00 = f00; r11 = f11;
                r01 = make_float2(wo * r01.x, wo * r01.y);
                r10 = make_float2(wo * r10.x, wo * r10.y);
            }
            if (i == 5) {
                *reinterpret_cast<float4*>(&dm[idx])      = make_float4(r00.x, r00.y, r01.x, r01.y);
                *reinterpret_cast<float4*>(&dm[idx + 64]) = make_float4(r10.x, r10.y, r11.x, r11.y);
            } else {
                dm[idx]           = r00;
                dm[idx | mb]      = r01;
                dm[idx | mk]      = r10;
                dm[idx | mk | mb] = r11;
            }
            __syncthreads();
        }
        // CNOT ring as one permutation, register-staged (in-place)
        {
            const int ri = rtab[l];
            float2 t[4];
            #pragma unroll
            for (int k = 0; k < 4; ++k) {
                int idx = tid + k * BLK;
                int K = idx >> 6, B = idx & 63;
                t[k] = dm[permtab[ri][K] * 64 + permtab[ri][B]];
            }
            __syncthreads();
            #pragma unroll
            for (int k = 0; k < 4; ++k) dm[tid + k * BLK] = t[k];
            __syncthreads();
        }
    }

    // ---------------- measurement (final deps on diagonal only) + head ----------------
    if (tid < 64) {
        float pr = dm[tid * (DIM + 1)].x;
        // final dep1 on each wire: diagonal mixes only with diagonal
        #pragma unroll
        for (int m = 1; m < 64; m <<= 1) {
            float other = __shfl_xor(pr, m, 64);
            pr = WD1 * pr + WX1 * other;
        }
        float ev[NQ];
        #pragma unroll
        for (int i = 0; i < NQ; ++i)
            ev[i] = ((tid >> (5 - i)) & 1) ? -pr : pr;
        #pragma unroll
        for (int off = 32; off > 0; off >>= 1) {
            #pragma unroll
            for (int i = 0; i < NQ; ++i) ev[i] += __shfl_down(ev[i], off, 64);
        }
        if (tid == 0) {
            #pragma unroll
            for (int j = 0; j < 2; ++j) {
                float o = bp[j];
                #pragma unroll
                for (int i = 0; i < NQ; ++i) o = fmaf(ev[i], Wp[j * NQ + i], o);
                out[b * 2 + j] = o;
            }
        }
    }
}

extern "C" void kernel_launch(void* const* d_in, const int* in_sizes, int n_in,
                              void* d_out, int out_size, void* d_ws, size_t ws_size,
                              hipStream_t stream) {
    (void)in_sizes; (void)n_in; (void)d_ws; (void)ws_size; (void)out_size;
    const float* x        = (const float*)d_in[0];
    const float* W1       = (const float*)d_in[1];
    const float* b1       = (const float*)d_in[2];
    const float* ln_g     = (const float*)d_in[3];
    const float* ln_b     = (const float*)d_in[4];
    const float* W2       = (const float*)d_in[5];
    const float* b2       = (const float*)d_in[6];
    const float* shared_w = (const float*)d_in[7];
    const float* task_w   = (const float*)d_in[8];
    const float* Wp       = (const float*)d_in[9];
    const float* bp       = (const float*)d_in[10];
    float* out = (float*)d_out;

    hipLaunchKernelGGL(nqm_kernel, dim3(256), dim3(BLK), 0, stream,
                       x, W1, b1, ln_g, ln_b, W2, b2, shared_w, task_w, Wp, bp, out);
}

// Round 3
// 118.683 us; speedup vs baseline: 1.6765x; 1.0079x over previous
//
#include <hip/hip_runtime.h>
#include <math.h>

#define NQ 6
#define DIM 64
#define DM_N 4096      // 64*64 density-matrix entries
#define BLK 1024
#define HID 256
#define INDIM 784

// depolarizing channel constants (diag mix wd/wx, off-diag scale wo)
#define PW1 0.001f
#define PW2 0.01f
constexpr float WD1 = 1.f - 2.f * PW1 / 3.f;
constexpr float WX1 = 2.f * PW1 / 3.f;
constexpr float WO1 = 1.f - 4.f * PW1 / 3.f;
constexpr float WD2 = 1.f - 2.f * PW2 / 3.f;
constexpr float WX2 = 2.f * PW2 / 3.f;
constexpr float WO2 = 1.f - 4.f * PW2 / 3.f;
// composition dep1 then dep2 on same wire
constexpr float WDc = WD1 * WD2 + WX1 * WX2;
constexpr float WXc = WD1 * WX2 + WX1 * WD2;
constexpr float WOc = WO1 * WO2;

__device__ __forceinline__ float2 cmul(float2 a, float2 b) {
    return make_float2(a.x * b.x - a.y * b.y, a.x * b.y + a.y * b.x);
}
__device__ __forceinline__ float2 cmulc(float2 a, float2 b) { // a * conj(b)
    return make_float2(a.x * b.x + a.y * b.y, a.y * b.x - a.x * b.y);
}
__device__ __forceinline__ float2 cadd(float2 a, float2 b) {
    return make_float2(a.x + b.x, a.y + b.y);
}

// DPP quad_perm cross-lane exchange (VALU pipe, no LDS, no sync needed)
#define DPP_X1 0xB1   // quad_perm [1,0,3,2] : lane ^ 1
#define DPP_X2 0x4E   // quad_perm [2,3,0,1] : lane ^ 2
#define DPP_X3 0x1B   // quad_perm [3,2,1,0] : lane ^ 3
template<int CTRL>
__device__ __forceinline__ float2 dpp2(float2 v) {
    int a = __builtin_amdgcn_update_dpp(0, __builtin_bit_cast(int, v.x), CTRL, 0xF, 0xF, true);
    int b = __builtin_amdgcn_update_dpp(0, __builtin_bit_cast(int, v.y), CTRL, 0xF, 0xF, true);
    return make_float2(__builtin_bit_cast(float, a), __builtin_bit_cast(float, b));
}

// rho -> U rho U^dag on the wire held in the thread's register-quad index
// e[j], j=(K<<1)|B for that wire
__device__ __forceinline__ void rot_reg(float2 e[4], float2 u0, float2 u1, float2 u2, float2 u3) {
    float2 t0 = cadd(cmul(u0, e[0]), cmul(u1, e[2]));
    float2 t1 = cadd(cmul(u0, e[1]), cmul(u1, e[3]));
    float2 t2 = cadd(cmul(u2, e[0]), cmul(u3, e[2]));
    float2 t3 = cadd(cmul(u2, e[1]), cmul(u3, e[3]));
    e[0] = cadd(cmulc(t0, u0), cmulc(t1, u1));
    e[1] = cadd(cmulc(t0, u2), cmulc(t1, u3));
    e[2] = cadd(cmulc(t2, u0), cmulc(t3, u1));
    e[3] = cadd(cmulc(t2, u2), cmulc(t3, u3));
}

// rho -> U rho U^dag on the wire held in lane bits (K=lane bit1, B=lane bit0)
__device__ __forceinline__ void rot_lane(float2 e[4], float2 u0, float2 u1, float2 u2, float2 u3,
                                         int kbit, int bbit) {
    // ket stage: partner across lane^2
    float2 cs = kbit ? u3 : u0;
    float2 co = kbit ? u2 : u1;
    #pragma unroll
    for (int j = 0; j < 4; ++j) {
        float2 w = dpp2<DPP_X2>(e[j]);
        e[j] = cadd(cmul(cs, e[j]), cmul(co, w));
    }
    // bra stage: partner across lane^1, conjugated coefficients
    cs = bbit ? u3 : u0;
    co = bbit ? u2 : u1;
    #pragma unroll
    for (int j = 0; j < 4; ++j) {
        float2 w = dpp2<DPP_X1>(e[j]);
        e[j] = cadd(cmulc(e[j], cs), cmulc(w, co));
    }
}

__device__ __forceinline__ void dep_reg(float2 e[4], float wd, float wx, float wo) {
    float2 a = e[0], d = e[3];
    e[0] = make_float2(wd * a.x + wx * d.x, wd * a.y + wx * d.y);
    e[3] = make_float2(wd * d.x + wx * a.x, wd * d.y + wx * a.y);
    e[1] = make_float2(wo * e[1].x, wo * e[1].y);
    e[2] = make_float2(wo * e[2].x, wo * e[2].y);
}

__device__ __forceinline__ void dep_lane(float2 e[4], float wd, float wx, float wo, bool dg) {
    float wa = dg ? wd : wo;
    float wb = dg ? wx : 0.0f;
    #pragma unroll
    for (int j = 0; j < 4; ++j) {
        float2 w = dpp2<DPP_X3>(e[j]);
        e[j] = make_float2(wa * e[j].x + wb * w.x, wa * e[j].y + wb * w.y);
    }
}

// Storage layout: interleaved s = [K0 B0 K1 B1 K2 B2 K3 B3 K4 B4 K5 B5] (bit 11..0).

__global__ __launch_bounds__(BLK)
void nqm_kernel(const float* __restrict__ x, const float* __restrict__ W1,
                const float* __restrict__ b1, const float* __restrict__ ln_g,
                const float* __restrict__ ln_b, const float* __restrict__ W2,
                const float* __restrict__ b2, const float* __restrict__ shared_w,
                const float* __restrict__ task_w, const float* __restrict__ Wp,
                const float* __restrict__ bp, float* __restrict__ out)
{
    __shared__ __align__(16) float2 dm[DM_N];   // 32 KB density matrix (interleaved layout)
    __shared__ float4 xrow[INDIM / 4];          // staged input row
    __shared__ float hpart[1024];               // 4-way split GEMM partials
    __shared__ float2 Umat[36][4];              // 6..35: Rot gates
    __shared__ float rho1q[NQ][4];              // initial per-qubit real 2x2 dms
    __shared__ int kstab[3][64];                // spread(pi_inv(v)) per ring r=1,2,3
    __shared__ float red[4], red2[4];           // layernorm wave partials
    __shared__ float zpart[4][8];               // z wave partials
    __shared__ float bcast[2];                  // mu, rstd

    const int tid = threadIdx.x;
    const int b = blockIdx.x;
    const int lane = tid & 63;
    const int kbit = (tid >> 1) & 1;            // lane-wire ket bit
    const int bbit = tid & 1;                   // lane-wire bra bit
    const bool dgl = (kbit == bbit);            // lane-wire diagonal?

    // ---------------- encoder: h = relu(x @ W1^T + b1) ----------------
    if (tid < INDIM / 4) xrow[tid] = ((const float4*)(x + (size_t)b * INDIM))[tid];
    __syncthreads();

    {   // 4 threads per hidden unit, 49 float4 each
        const int u = tid & 255, p = tid >> 8;
        const float4* w1v = (const float4*)(W1 + (size_t)u * INDIM) + p * 49;
        const float4* xv4 = xrow + p * 49;
        float acc = 0.0f;
        #pragma unroll 7
        for (int k = 0; k < 49; ++k) {
            float4 wv = w1v[k];
            float4 xv = xv4[k];
            acc = fmaf(wv.x, xv.x, acc);
            acc = fmaf(wv.y, xv.y, acc);
            acc = fmaf(wv.z, xv.z, acc);
            acc = fmaf(wv.w, xv.w, acc);
        }
        hpart[p * 256 + u] = acc;
    }
    __syncthreads();

    float h = 0.0f;
    if (tid < 256) {
        h = hpart[tid] + hpart[256 + tid] + hpart[512 + tid] + hpart[768 + tid] + b1[tid];
        h = fmaxf(h, 0.0f);
        float s = h, s2 = h * h;
        #pragma unroll
        for (int off = 32; off > 0; off >>= 1) {
            s  += __shfl_down(s, off, 64);
            s2 += __shfl_down(s2, off, 64);
        }
        if (lane == 0) { red[tid >> 6] = s; red2[tid >> 6] = s2; }
    }
    __syncthreads();
    if (tid == 0) {
        float ts  = red[0] + red[1] + red[2] + red[3];
        float ts2 = red2[0] + red2[1] + red2[2] + red2[3];
        float mu  = ts * (1.0f / HID);
        float var = ts2 * (1.0f / HID) - mu * mu;
        bcast[0] = mu;
        bcast[1] = rsqrtf(var + 1e-5f);
    }
    __syncthreads();
    if (tid < 256) {
        float hnj = (h - bcast[0]) * bcast[1] * ln_g[tid] + ln_b[tid];
        float p[NQ];
        #pragma unroll
        for (int i = 0; i < NQ; ++i) p[i] = hnj * W2[i * HID + tid];
        #pragma unroll
        for (int off = 32; off > 0; off >>= 1) {
            #pragma unroll
            for (int i = 0; i < NQ; ++i) p[i] += __shfl_down(p[i], off, 64);
        }
        if (lane == 0) {
            #pragma unroll
            for (int i = 0; i < NQ; ++i) zpart[tid >> 6][i] = p[i];
        }
    }
    __syncthreads();

    // ------------- gate matrices, init dms, ring spread-tables -------------
    if (tid < NQ) {
        float z = zpart[0][tid] + zpart[1][tid] + zpart[2][tid] + zpart[3][tid] + b2[tid];
        z = tanhf(z);
        float sn, c;
        sincosf(z * 1.57079632679489662f, &sn, &c);
        float c2 = c * c, s2 = sn * sn, cs = c * sn;
        rho1q[tid][0] = WD1 * c2 + WX1 * s2;  // [K=0][B=0]
        rho1q[tid][1] = WO1 * cs;             // [0][1]
        rho1q[tid][2] = WO1 * cs;             // [1][0]
        rho1q[tid][3] = WD1 * s2 + WX1 * c2;  // [1][1]
    } else if (tid < 36) {
        // Rot(phi,theta,omega) = RZ(omega) RY(theta) RZ(phi)
        int g = tid - NQ;
        int layer = g / NQ;
        int wire = g % NQ;
        const float* w = (layer < 3) ? (shared_w + (layer * NQ + wire) * 3)
                                     : (task_w + ((layer - 3) * NQ + wire) * 3);
        float phi = w[0], theta = w[1], omega = w[2];
        float sn, c;
        sincosf(theta * 0.5f, &sn, &c);
        float sp, cp, sm, cm;
        sincosf(-0.5f * (phi + omega), &sp, &cp);  // ep = cp + i*sp
        sincosf( 0.5f * (phi - omega), &sm, &cm);  // em = cm + i*sm
        Umat[tid][0] = make_float2(cp * c,   sp * c);   // ep*c
        Umat[tid][1] = make_float2(-cm * sn, -sm * sn); // -em*s
        Umat[tid][2] = make_float2(cm * sn,  -sm * sn); // conj(em)*s
        Umat[tid][3] = make_float2(cp * c,   -sp * c);  // conj(ep)*c
    } else if (tid < 36 + 3 * 64) {
        // kstab[ri][v] = spread(pi_inv(v)) for CNOT ring r = ri+1
        int t = tid - 36;
        int ri = t >> 6, s = t & 63, r = ri + 1;
        int v = s;
        #pragma unroll
        for (int i = 5; i >= 0; --i) {
            int tw = (i + r) % 6;
            if ((v >> (5 - i)) & 1) v ^= 1 << (5 - tw);
        }
        int sp = 0;
        #pragma unroll
        for (int j = 0; j < 6; ++j) sp |= ((v >> j) & 1) << (2 * j + 1);
        kstab[ri][s] = sp;
    }

    // per-thread logical ket/bra high bits for pass-0 mapping s = tid*4 + r
    // k = (s11,s9,s7,s5,s3,s1), b = (s10,s8,s6,s4,s2,s0); bit0 of each comes from r
    const int t = tid;
    const int tk = (((t >> 9) & 1) << 5) | (((t >> 7) & 1) << 4) | (((t >> 5) & 1) << 3)
                 | (((t >> 3) & 1) << 2) | (((t >> 1) & 1) << 1);
    const int tb = (((t >> 8) & 1) << 5) | (((t >> 6) & 1) << 4) | (((t >> 4) & 1) << 3)
                 | (((t >> 2) & 1) << 2) | ((t & 1) << 1);
    const int base1 = ((t & 0x3C0) << 2) | ((t & 3) << 6) | ((t >> 2) & 15);   // pass-1 slots (+16*r)
    const int base2 = ((t & 3) << 10) | ((t >> 2) & 0xFF);                     // pass-2 slots (+256*r)
    const int rtab[5] = {0, 1, 2, 0, 1};  // ring table index (r-1) after layer l
    __syncthreads();

    // ---------------- 5 entangling layers, 3 fused passes each ----------------
    for (int l = 0; l < 5; ++l) {
        const int g0 = 6 + l * 6;
        float2 e[4];

        // ---- pass 0: wire 5 in registers, wire 4 on lanes ----
        if (l == 0) {
            // analytic product state: dep(RY|0><0|RY^T) per qubit, all real
            float A = 1.0f;
            #pragma unroll
            for (int w = 0; w < 5; ++w) {
                int Kw = (tk >> (5 - w)) & 1, Bw = (tb >> (5 - w)) & 1;
                A *= rho1q[w][Kw * 2 + Bw];
            }
            e[0] = make_float2(A * rho1q[5][0], 0.f);
            e[1] = make_float2(A * rho1q[5][1], 0.f);
            e[2] = make_float2(A * rho1q[5][2], 0.f);
            e[3] = make_float2(A * rho1q[5][3], 0.f);
        } else {
            // gather with previous layer's CNOT-ring perm folded in
            const int* ks = kstab[rtab[l - 1]];
            int a0 = ks[tk], a1 = ks[tk | 1];
            int c0 = ks[tb] >> 1, c1 = ks[tb | 1] >> 1;
            e[0] = dm[a0 | c0];
            e[1] = dm[a0 | c1];
            e[2] = dm[a1 | c0];
            e[3] = dm[a1 | c1];
            __syncthreads();
        }
        rot_reg(e, Umat[g0 + 5][0], Umat[g0 + 5][1], Umat[g0 + 5][2], Umat[g0 + 5][3]);
        rot_lane(e, Umat[g0 + 4][0], Umat[g0 + 4][1], Umat[g0 + 4][2], Umat[g0 + 4][3], kbit, bbit);
        if (l == 3) {
            dep_reg(e, WD1, WX1, WO1);          // wire 5: dep1 only
            dep_lane(e, WDc, WXc, WOc, dgl);    // wire 4: dep1+dep2 combo
        }
        *(float4*)&dm[t * 4]     = make_float4(e[0].x, e[0].y, e[1].x, e[1].y);
        *(float4*)&dm[t * 4 + 2] = make_float4(e[2].x, e[2].y, e[3].x, e[3].y);
        __syncthreads();

        // ---- pass 1: wire 3 in registers, wire 2 on lanes (in-place slots) ----
        e[0] = dm[base1];
        e[1] = dm[base1 + 16];
        e[2] = dm[base1 + 32];
        e[3] = dm[base1 + 48];
        rot_reg(e, Umat[g0 + 3][0], Umat[g0 + 3][1], Umat[g0 + 3][2], Umat[g0 + 3][3]);
        rot_lane(e, Umat[g0 + 2][0], Umat[g0 + 2][1], Umat[g0 + 2][2], Umat[g0 + 2][3], kbit, bbit);
        if (l == 3) {
            dep_reg(e, WDc, WXc, WOc);
            dep_lane(e, WDc, WXc, WOc, dgl);
        }
        dm[base1]      = e[0];
        dm[base1 + 16] = e[1];
        dm[base1 + 32] = e[2];
        dm[base1 + 48] = e[3];
        __syncthreads();

        // ---- pass 2: wire 1 in registers, wire 0 on lanes (in-place slots) ----
        e[0] = dm[base2];
        e[1] = dm[base2 + 256];
        e[2] = dm[base2 + 512];
        e[3] = dm[base2 + 768];
        rot_reg(e, Umat[g0 + 1][0], Umat[g0 + 1][1], Umat[g0 + 1][2], Umat[g0 + 1][3]);
        rot_lane(e, Umat[g0 + 0][0], Umat[g0 + 0][1], Umat[g0 + 0][2], Umat[g0 + 0][3], kbit, bbit);
        if (l == 3) {
            dep_reg(e, WDc, WXc, WOc);
            dep_lane(e, WDc, WXc, WOc, dgl);
        }
        dm[base2]       = e[0];
        dm[base2 + 256] = e[1];
        dm[base2 + 512] = e[2];
        dm[base2 + 768] = e[3];
        __syncthreads();
    }

    // -------- measurement: fold last ring perm + final deps on diagonal --------
    if (tid < 64) {
        int sp = kstab[1][tid];               // ring after task layer 2: r=2
        float pr = dm[sp | (sp >> 1)].x;      // diag entry (pi_inv(d), pi_inv(d))
        // final dep1 on each wire: diagonal mixes only with diagonal
        #pragma unroll
        for (int m = 1; m < 64; m <<= 1) {
            float other = __shfl_xor(pr, m, 64);
            pr = WD1 * pr + WX1 * other;
        }
        float ev[NQ];
        #pragma unroll
        for (int i = 0; i < NQ; ++i)
            ev[i] = ((tid >> (5 - i)) & 1) ? -pr : pr;
        #pragma unroll
        for (int off = 32; off > 0; off >>= 1) {
            #pragma unroll
            for (int i = 0; i < NQ; ++i) ev[i] += __shfl_down(ev[i], off, 64);
        }
        if (tid == 0) {
            #pragma unroll
            for (int j = 0; j < 2; ++j) {
                float o = bp[j];
                #pragma unroll
                for (int i = 0; i < NQ; ++i) o = fmaf(ev[i], Wp[j * NQ + i], o);
                out[b * 2 + j] = o;
            }
        }
    }
}

extern "C" void kernel_launch(void* const* d_in, const int* in_sizes, int n_in,
                              void* d_out, int out_size, void* d_ws, size_t ws_size,
                              hipStream_t stream) {
    (void)in_sizes; (void)n_in; (void)d_ws; (void)ws_size; (void)out_size;
    const float* x        = (const float*)d_in[0];
    const float* W1       = (const float*)d_in[1];
    const float* b1       = (const float*)d_in[2];
    const float* ln_g     = (const float*)d_in[3];
    const float* ln_b     = (const float*)d_in[4];
    const float* W2       = (const float*)d_in[5];
    const float* b2       = (const float*)d_in[6];
    const float* shared_w = (const float*)d_in[7];
    const float* task_w   = (const float*)d_in[8];
    const float* Wp       = (const float*)d_in[9];
    const float* bp       = (const float*)d_in[10];
    float* out = (float*)d_out;

    hipLaunchKernelGGL(nqm_kernel, dim3(256), dim3(BLK), 0, stream,
                       x, W1, b1, ln_g, ln_b, W2, b2, shared_w, task_w, Wp, bp, out);
}

// Round 5
// 102.467 us; speedup vs baseline: 1.9418x; 1.1583x over previous
//
#include <hip/hip_runtime.h>
#include <math.h>

#define NQ 6
#define BLK 1024
#define HID 256
#define INDIM 784

#define PW1 0.001f
#define PW2 0.01f
constexpr float WO1 = 1.f - 4.f * PW1 / 3.f;   // dep1 Bloch shrink
constexpr float WO2 = 1.f - 4.f * PW2 / 3.f;   // dep2 Bloch shrink
constexpr float WOc = WO1 * WO2;               // combined mid-circuit dep

// ---------- compile-time CNOT-ring tables (inverse map + sign) ----------
// Pauli string: wire w -> bits (x_w at 2w+1, z_w at 2w). Code q=(x<<1)|z: 0=I,1=Z,2=X,3=Y.
// CNOT(c->t) conjugation (CHP rule): sign ^= x_c z_t (x_t ^ z_c ^ 1); x_t ^= x_c; z_c ^= z_t.
// Need U^dag P U for ring U = C5..C0 (C0 applied first): conjugate by C5 first, ... C0 last.
struct alignas(16) RingTabs { int t[3][4096]; };
constexpr RingTabs make_ring_tabs() {
    RingTabs R{};
    for (int ri = 0; ri < 3; ++ri) {
        int r = ri + 1;
        for (int v = 0; v < 4096; ++v) {
            int x[6], z[6];
            for (int w = 0; w < 6; ++w) { x[w] = (v >> (2 * w + 1)) & 1; z[w] = (v >> (2 * w)) & 1; }
            int sgn = 0;
            for (int i = 5; i >= 0; --i) {
                int c = i, tg = (i + r) % 6;
                sgn ^= x[c] & z[tg] & (x[tg] ^ z[c] ^ 1);
                x[tg] ^= x[c];
                z[c]  ^= z[tg];
            }
            int s = 0;
            for (int w = 0; w < 6; ++w) s |= (x[w] << (2 * w + 1)) | (z[w] << (2 * w));
            R.t[ri][v] = s | (sgn << 31);
        }
    }
    return R;
}
static __device__ const RingTabs RT = make_ring_tabs();

// LDS bank swizzle: injects lane-varying bits (n[7:6]^n[11:10]) into bank bits [4:3].
// Makes P0 (b128 contiguous), P1 (stride-16), P2 (stride-256) accesses conflict-free.
__device__ __forceinline__ int swz(int n) {
    return n ^ ((((n >> 6) ^ (n >> 10)) & 3) << 3);
}

// DPP quad broadcasts (get quad-lane k's value), pure VALU, no sync needed
template<int CTRL>
__device__ __forceinline__ float qb(float v) {
    int r = __builtin_amdgcn_update_dpp(0, __builtin_bit_cast(int, v), CTRL, 0xF, 0xF, true);
    return __builtin_bit_cast(float, r);
}

// Gate on the register wire: e[1]=Z,e[2]=X,e[3]=Y mixed by M rows (rX,rY,rZ as float4)
__device__ __forceinline__ void rot_reg(float e[4], float4 rZ, float4 rX, float4 rY) {
    float X = e[2], Y = e[3], Z = e[1];
    e[2] = fmaf(rX.x, X, fmaf(rX.y, Y, rX.z * Z));
    e[3] = fmaf(rY.x, X, fmaf(rY.y, Y, rY.z * Z));
    e[1] = fmaf(rZ.x, X, fmaf(rZ.y, Y, rZ.z * Z));
}

// Gate on the lane wire (quad position p = tid&3 is the Pauli code); cf = (cX,cY,cZ,keep)
__device__ __forceinline__ void rot_lane(float e[4], float4 cf) {
    #pragma unroll
    for (int j = 0; j < 4; ++j) {
        float vZ = qb<0x55>(e[j]);   // quad lane 1 (Z)
        float vX = qb<0xAA>(e[j]);   // quad lane 2 (X)
        float vY = qb<0xFF>(e[j]);   // quad lane 3 (Y)
        e[j] = fmaf(cf.x, vX, fmaf(cf.y, vY, fmaf(cf.z, vZ, cf.w * e[j])));
    }
}

// Layout: n = (q5<<10)|(q4<<8)|(q3<<6)|(q2<<4)|(q1<<2)|q0, all accesses via swz(n).
// P0: reg wire0 (n[1:0]), lane wire1 (t[1:0]);  P1: reg wire2, lane wire3;  P2: reg wire4, lane wire5.

__global__ __launch_bounds__(BLK)
void nqm_kernel(const float* __restrict__ x, const float* __restrict__ W1,
                const float* __restrict__ b1, const float* __restrict__ ln_g,
                const float* __restrict__ ln_b, const float* __restrict__ W2,
                const float* __restrict__ b2, const float* __restrict__ shared_w,
                const float* __restrict__ task_w, const float* __restrict__ Wp,
                const float* __restrict__ bp, float* __restrict__ out)
{
    __shared__ __align__(16) float dm[4096];     // 16 KB Pauli coefficients
    __shared__ float4 xrow[INDIM / 4];
    __shared__ float hpart[1024];
    __shared__ __align__(16) float4 Mlane[30][4]; // per gate: rows for quad-pos p (cX,cY,cZ,keep)
    __shared__ float bloch[NQ][4];               // initial per-qubit coeffs [1, WO1*c, WO1*s, 0]
    __shared__ float red[4], red2[4];
    __shared__ float zpart[4][8];
    __shared__ float bcast[2];
    __shared__ float evs[8];

    const int tid = threadIdx.x;
    const int b = blockIdx.x;
    const int lane = tid & 63;
    const int qpos = tid & 3;                    // lane-wire Pauli code

    // ---------------- encoder: h = relu(x @ W1^T + b1) ----------------
    if (tid < INDIM / 4) xrow[tid] = ((const float4*)(x + (size_t)b * INDIM))[tid];
    __syncthreads();

    {   // 4 threads per hidden unit, 49 float4 each
        const int u = tid & 255, p = tid >> 8;
        const float4* w1v = (const float4*)(W1 + (size_t)u * INDIM) + p * 49;
        const float4* xv4 = xrow + p * 49;
        float acc = 0.0f;
        #pragma unroll 7
        for (int k = 0; k < 49; ++k) {
            float4 wv = w1v[k];
            float4 xv = xv4[k];
            acc = fmaf(wv.x, xv.x, acc);
            acc = fmaf(wv.y, xv.y, acc);
            acc = fmaf(wv.z, xv.z, acc);
            acc = fmaf(wv.w, xv.w, acc);
        }
        hpart[p * 256 + u] = acc;
    }
    __syncthreads();

    float h = 0.0f;
    if (tid < 256) {
        h = hpart[tid] + hpart[256 + tid] + hpart[512 + tid] + hpart[768 + tid] + b1[tid];
        h = fmaxf(h, 0.0f);
        float s = h, s2 = h * h;
        #pragma unroll
        for (int off = 32; off > 0; off >>= 1) {
            s  += __shfl_down(s, off, 64);
            s2 += __shfl_down(s2, off, 64);
        }
        if (lane == 0) { red[tid >> 6] = s; red2[tid >> 6] = s2; }
    }
    __syncthreads();
    if (tid == 0) {
        float ts  = red[0] + red[1] + red[2] + red[3];
        float ts2 = red2[0] + red2[1] + red2[2] + red2[3];
        float mu  = ts * (1.0f / HID);
        float var = ts2 * (1.0f / HID) - mu * mu;
        bcast[0] = mu;
        bcast[1] = rsqrtf(var + 1e-5f);
    }
    __syncthreads();
    if (tid < 256) {
        float hnj = (h - bcast[0]) * bcast[1] * ln_g[tid] + ln_b[tid];
        float p[NQ];
        #pragma unroll
        for (int i = 0; i < NQ; ++i) p[i] = hnj * W2[i * HID + tid];
        #pragma unroll
        for (int off = 32; off > 0; off >>= 1) {
            #pragma unroll
            for (int i = 0; i < NQ; ++i) p[i] += __shfl_down(p[i], off, 64);
        }
        if (lane == 0) {
            #pragma unroll
            for (int i = 0; i < NQ; ++i) zpart[tid >> 6][i] = p[i];
        }
    }
    __syncthreads();

    // ------------- gate SO(3) matrices + initial Bloch vectors -------------
    if (tid < NQ) {
        float z = zpart[0][tid] + zpart[1][tid] + zpart[2][tid] + zpart[3][tid] + b2[tid];
        z = tanhf(z);
        float sn, c;
        sincosf(z * 3.14159265358979323846f, &sn, &c);  // full angle for Bloch vector
        bloch[tid][0] = 1.0f;
        bloch[tid][1] = WO1 * c;    // Z
        bloch[tid][2] = WO1 * sn;   // X
        bloch[tid][3] = 0.0f;       // Y
    } else if (tid < 36) {          // threads 6..35 -> gates 0..29 (EXACTLY 30 gates)
        int g = tid - NQ;
        int layer = g / NQ;
        int wire = g % NQ;
        const float* w = (layer < 3) ? (shared_w + (layer * NQ + wire) * 3)
                                     : (task_w + ((layer - 3) * NQ + wire) * 3);
        float phi = w[0], theta = w[1], omega = w[2];
        float sf, cf_, st, ct, so, co;
        sincosf(phi, &sf, &cf_);
        sincosf(theta, &st, &ct);
        sincosf(omega, &so, &co);
        // M = Mz(omega) * My(theta) * Mz(phi)  (SO(3), Bloch rotation of Rot conjugation)
        float M00 = co * ct * cf_ - so * sf;
        float M01 = -co * ct * sf - so * cf_;
        float M02 = co * st;
        float M10 = so * ct * cf_ + co * sf;
        float M11 = -so * ct * sf + co * cf_;
        float M12 = so * st;
        float M20 = -st * cf_;
        float M21 = st * sf;
        float M22 = ct;
        // bake mid-circuit deps into task layer 1 (layer==3) gates
        float f = (layer == 3) ? ((wire < 5) ? WOc : WO1) : 1.0f;
        Mlane[g][0] = make_float4(0.f, 0.f, 0.f, 1.f);                    // p=0 (I): keep
        Mlane[g][1] = make_float4(f * M20, f * M21, f * M22, 0.f);        // p=1 (Z): row Z
        Mlane[g][2] = make_float4(f * M00, f * M01, f * M02, 0.f);        // p=2 (X): row X
        Mlane[g][3] = make_float4(f * M10, f * M11, f * M12, 0.f);        // p=3 (Y): row Y
    }

    // per-pass slot bases (see layout comment)
    const int t = tid;
    const int base1 = ((t & 0x3C0) << 2) | ((t & 3) << 6) | ((t >> 2) & 0xF);   // P1: +16*j
    const int base2 = ((t & 3) << 10) | ((t >> 2) & 0xFF);                      // P2: +256*j
    __syncthreads();

    // ---------------- 5 entangling layers ----------------
    const int rtab[4] = {0, 1, 2, 0};   // ring table idx folded into gather at layer l (=ring after l-1)
    for (int l = 0; l < 5; ++l) {
        const int g0 = l * 6;
        float e[4];

        // ---- P0: reg wire0, lane wire1 ----
        if (l == 0) {
            // product state: A over wires 1..5, times wire0 components
            float A = bloch[1][t & 3] * bloch[2][(t >> 2) & 3] * bloch[3][(t >> 4) & 3]
                    * bloch[4][(t >> 6) & 3] * bloch[5][(t >> 8) & 3];
            e[0] = A * bloch[0][0];
            e[1] = A * bloch[0][1];
            e[2] = A * bloch[0][2];
            e[3] = A * bloch[0][3];
        } else {
            // gather previous layer's CNOT ring (inverse map + sign) from compile-time table
            const int4 te = *(const int4*)&RT.t[rtab[l - 1]][t << 2];
            float v0 = dm[swz(te.x & 4095)];
            float v1 = dm[swz(te.y & 4095)];
            float v2 = dm[swz(te.z & 4095)];
            float v3 = dm[swz(te.w & 4095)];
            e[0] = __int_as_float(__float_as_int(v0) ^ (te.x & 0x80000000));
            e[1] = __int_as_float(__float_as_int(v1) ^ (te.y & 0x80000000));
            e[2] = __int_as_float(__float_as_int(v2) ^ (te.z & 0x80000000));
            e[3] = __int_as_float(__float_as_int(v3) ^ (te.w & 0x80000000));
            __syncthreads();
        }
        {
            float4 rZ = Mlane[g0 + 0][1], rX = Mlane[g0 + 0][2], rY = Mlane[g0 + 0][3];
            rot_reg(e, rZ, rX, rY);
            rot_lane(e, Mlane[g0 + 1][qpos]);
        }
        *(float4*)&dm[swz(t << 2)] = make_float4(e[0], e[1], e[2], e[3]);
        __syncthreads();

        // ---- P1: reg wire2, lane wire3 ----
        e[0] = dm[swz(base1)];
        e[1] = dm[swz(base1 + 16)];
        e[2] = dm[swz(base1 + 32)];
        e[3] = dm[swz(base1 + 48)];
        {
            float4 rZ = Mlane[g0 + 2][1], rX = Mlane[g0 + 2][2], rY = Mlane[g0 + 2][3];
            rot_reg(e, rZ, rX, rY);
            rot_lane(e, Mlane[g0 + 3][qpos]);
        }
        dm[swz(base1)]      = e[0];
        dm[swz(base1 + 16)] = e[1];
        dm[swz(base1 + 32)] = e[2];
        dm[swz(base1 + 48)] = e[3];
        __syncthreads();

        // ---- P2: reg wire4, lane wire5 ----
        e[0] = dm[swz(base2)];
        e[1] = dm[swz(base2 + 256)];
        e[2] = dm[swz(base2 + 512)];
        e[3] = dm[swz(base2 + 768)];
        {
            float4 rZ = Mlane[g0 + 4][1], rX = Mlane[g0 + 4][2], rY = Mlane[g0 + 4][3];
            rot_reg(e, rZ, rX, rY);
            rot_lane(e, Mlane[g0 + 5][qpos]);
        }
        dm[swz(base2)]       = e[0];
        dm[swz(base2 + 256)] = e[1];
        dm[swz(base2 + 512)] = e[2];
        dm[swz(base2 + 768)] = e[3];
        __syncthreads();
    }

    // ---- readout: fold final ring (r=2 -> table 1) + final dep1 + linear head ----
    if (tid < NQ) {
        int e = RT.t[1][1 << (2 * tid)];            // Z on wire tid
        float v = dm[swz(e & 4095)];
        v = __int_as_float(__float_as_int(v) ^ (e & 0x80000000));
        evs[tid] = WO1 * v;
    }
    __syncthreads();
    if (tid < 2) {
        float o = bp[tid];
        #pragma unroll
        for (int i = 0; i < NQ; ++i) o = fmaf(evs[i], Wp[tid * NQ + i], o);
        out[b * 2 + tid] = o;
    }
}

extern "C" void kernel_launch(void* const* d_in, const int* in_sizes, int n_in,
                              void* d_out, int out_size, void* d_ws, size_t ws_size,
                              hipStream_t stream) {
    (void)in_sizes; (void)n_in; (void)d_ws; (void)ws_size; (void)out_size;
    const float* x        = (const float*)d_in[0];
    const float* W1       = (const float*)d_in[1];
    const float* b1       = (const float*)d_in[2];
    const float* ln_g     = (const float*)d_in[3];
    const float* ln_b     = (const float*)d_in[4];
    const float* W2       = (const float*)d_in[5];
    const float* b2       = (const float*)d_in[6];
    const float* shared_w = (const float*)d_in[7];
    const float* task_w   = (const float*)d_in[8];
    const float* Wp       = (const float*)d_in[9];
    const float* bp       = (const float*)d_in[10];
    float* out = (float*)d_out;

    hipLaunchKernelGGL(nqm_kernel, dim3(256), dim3(BLK), 0, stream,
                       x, W1, b1, ln_g, ln_b, W2, b2, shared_w, task_w, Wp, bp, out);
}